// Round 7
// baseline (234.608 us; speedup 1.0000x reference)
//
#include <hip/hip_runtime.h>
#include <hip/hip_bf16.h>

// out[s,b,o] = sum_h in[s,b,h] * w[o,h]
// A = [M=8192, K=1024] fp32, W = [N=4096, K=1024] fp32 (B^T layout), C = [M,N] fp32.
//
// Round 8: EXACT revert to the round-2 (81.5us) double-barrier 8-phase kernel —
// the best verified body; all schedule variants (single-barrier 90, pipelined-read
// 84.8) regressed because frag registers are single-buffered at the 256-reg wall.
// Decomposition: K-loop pace already equals the m201 template (4013 vs 4005
// cyc/K-tile); the remaining gap is 2 rounds x ~14us fixed cost, dominated by the
// end-of-block C-store burst + write-allocate RMW (proved by R4's FETCH 77->51MB).
// This round changes ONLY the epilogue: nontemporal dword stores (no line fetch,
// no L2/L3 pollution of A/B panels) ordered (i, r, j) so the four 64B segments of
// each C row issue back-to-back for write-combining.
//
// Stage-unit ledger (verified passing, unchanged):
//   ph1 E.q(0,0) reads A0,B0  stages O.u2    ph2 E.q(0,1) reads B1  stages O.u3
//   ph3 E.q(1,1) reads A1     stages E+2.u1  ph4 E.q(1,0)           stages E+2.u4  GATE vmcnt(4)
//   ph5 O.q(0,0) reads A0,B0  stages E+2.u3  ph6 O.q(0,1) reads B1  stages E+2.u2
//   ph7 O.q(1,1) reads A1     stages E+3.u1  ph8 O.q(1,0)           stages E+3.u4  GATE vmcnt(4)
// Every stage >=2 barriers after its region's last read; each gate leaves 2 units
// (4 loads) in flight, guaranteeing the next tile's 4 units have landed. Tail
// iterations clamp stage k0 to the last tile (garbage into dead regions, in-bounds).

typedef __bf16 bf16x8_t __attribute__((ext_vector_type(8)));
typedef float f32x4_t __attribute__((ext_vector_type(4)));

constexpr int M = 8192;
constexpr int N = 4096;
constexpr int K = 1024;
constexpr int BM = 256;
constexpr int BN = 256;
constexpr int BK = 64;

// ---------------- fp32 -> bf16 convert, both tensors in one launch ----------
__global__ __launch_bounds__(256) void cvt_f32_bf16(const float* __restrict__ a,
                                                    const float* __restrict__ w,
                                                    __bf16* __restrict__ a_bf,
                                                    __bf16* __restrict__ w_bf) {
    size_t i = ((size_t)blockIdx.x * 256 + threadIdx.x) * 8;
    const float* src;
    __bf16* dst;
    if (i < (size_t)M * K) {
        src = a + i;
        dst = a_bf + i;
    } else {
        size_t j = i - (size_t)M * K;
        src = w + j;
        dst = w_bf + j;
    }
    float4 v0 = *(const float4*)(src);
    float4 v1 = *(const float4*)(src + 4);
    bf16x8_t o;
    o[0] = (__bf16)v0.x; o[1] = (__bf16)v0.y; o[2] = (__bf16)v0.z; o[3] = (__bf16)v0.w;
    o[4] = (__bf16)v1.x; o[5] = (__bf16)v1.y; o[6] = (__bf16)v1.z; o[7] = (__bf16)v1.w;
    *(bf16x8_t*)dst = o;
}

// ---------------- bf16 GEMM, 256x256 tile, 8-phase counted-vmcnt pipeline ----
__global__ __launch_bounds__(512, 1) void gemm_bt(const __bf16* __restrict__ A,
                                                  const __bf16* __restrict__ B,
                                                  float* __restrict__ C) {
    // [buf][0=A,1=B][row][col]; row stride 64 bf16 = 128 B = 8 chunks of 16 B.
    // LDS slot (row, chunk c) holds global chunk c ^ (row & 7)  (both-sides involution).
    __shared__ __bf16 lds[2][2][256][BK];   // 128 KiB

    const int tid = threadIdx.x;
    const int lane = tid & 63;
    const int quad = lane >> 4;
    const int l16 = lane & 15;
    const int sa = l16 & 7;            // read-side swizzle key (= frag row & 7)
    const int wave = tid >> 6;         // 8 waves, 2(M) x 4(N)
    const int wm = wave >> 2;
    const int wn = wave & 3;

    const int bm = blockIdx.y * BM;
    const int bn = blockIdx.x * BN;

    // staging per-thread geometry
    const int c8 = tid & 7;            // 16B chunk within a row
    const int r8 = (tid >> 3) & 7;     // dst row & 7 for every stage pattern
    const int scol = (c8 ^ r8) << 3;   // pre-swizzled global source column (elems)
    const int arow = tid >> 3;         // 0..63
    const int bq64 = ((tid >> 8) << 6);// 0 or 64
    const int brow = (tid >> 3) & 31;  // 0..31

    f32x4_t acc[8][4] = {};

#define STAGE_A(buf, mh, k0)                                                        \
  do {                                                                              \
    _Pragma("unroll") for (int r_ = 0; r_ < 2; ++r_) {                              \
      int row_ = r_ * 128 + (mh) * 64 + arow;                                       \
      __builtin_amdgcn_global_load_lds(                                             \
          (const __attribute__((address_space(1))) unsigned int*)(                  \
              A + (size_t)(bm + row_) * K + (k0) + scol),                           \
          (__attribute__((address_space(3))) unsigned int*)(&lds[buf][0][row_][c8 * 8]), \
          16, 0, 0);                                                                \
    }                                                                               \
  } while (0)

#define STAGE_B(buf, nh, k0)                                                        \
  do {                                                                              \
    _Pragma("unroll") for (int r_ = 0; r_ < 2; ++r_) {                              \
      int row_ = r_ * 128 + bq64 + (nh) * 32 + brow;                                \
      __builtin_amdgcn_global_load_lds(                                             \
          (const __attribute__((address_space(1))) unsigned int*)(                  \
              B + (size_t)(bn + row_) * K + (k0) + scol),                           \
          (__attribute__((address_space(3))) unsigned int*)(&lds[buf][1][row_][c8 * 8]), \
          16, 0, 0);                                                                \
    }                                                                               \
  } while (0)

#define LOAD_A(buf, mh)                                                             \
  do {                                                                              \
    _Pragma("unroll") for (int i_ = 0; i_ < 4; ++i_) {                              \
      int row_ = wm * 128 + (mh) * 64 + i_ * 16 + l16;                              \
      _Pragma("unroll") for (int ks_ = 0; ks_ < 2; ++ks_)                           \
        a[i_][ks_] = *(const bf16x8_t*)(&lds[buf][0][row_][((ks_ * 4 + quad) ^ sa) << 3]); \
    }                                                                               \
  } while (0)

#define LOAD_B(buf, nh, bv)                                                         \
  do {                                                                              \
    _Pragma("unroll") for (int j_ = 0; j_ < 2; ++j_) {                              \
      int row_ = wn * 64 + (nh) * 32 + j_ * 16 + l16;                               \
      _Pragma("unroll") for (int ks_ = 0; ks_ < 2; ++ks_)                           \
        bv[j_][ks_] = *(const bf16x8_t*)(&lds[buf][1][row_][((ks_ * 4 + quad) ^ sa) << 3]); \
    }                                                                               \
  } while (0)

#define MFMA_Q(mh, nh, bv)                                                          \
  do {                                                                              \
    __builtin_amdgcn_s_setprio(1);                                                  \
    _Pragma("unroll") for (int i_ = 0; i_ < 4; ++i_)                                \
      _Pragma("unroll") for (int j_ = 0; j_ < 2; ++j_) {                            \
        acc[(mh) * 4 + i_][(nh) * 2 + j_] = __builtin_amdgcn_mfma_f32_16x16x32_bf16( \
            a[i_][0], bv[j_][0], acc[(mh) * 4 + i_][(nh) * 2 + j_], 0, 0, 0);       \
        acc[(mh) * 4 + i_][(nh) * 2 + j_] = __builtin_amdgcn_mfma_f32_16x16x32_bf16( \
            a[i_][1], bv[j_][1], acc[(mh) * 4 + i_][(nh) * 2 + j_], 0, 0, 0);       \
      }                                                                             \
    __builtin_amdgcn_s_setprio(0);                                                  \
  } while (0)

#define FENCE() asm volatile("" ::: "memory")
#define BAR()   do { FENCE(); __builtin_amdgcn_s_barrier(); FENCE(); } while (0)
#define LGKM0() asm volatile("s_waitcnt lgkmcnt(0)" ::: "memory")
#define VMCNT(n_) asm volatile("s_waitcnt vmcnt(" #n_ ")" ::: "memory")

    // Prologue: tile0 fully + tile1.{u1,u4}. vmcnt(4) = first 8 of 12 loads landed
    // = all of tile0.
    STAGE_A(0, 0, 0);      // t0.u1
    STAGE_B(0, 0, 0);      // t0.u2
    STAGE_B(0, 1, 0);      // t0.u4
    STAGE_A(0, 1, 0);      // t0.u3
    STAGE_A(1, 0, BK);     // t1.u1
    STAGE_B(1, 1, BK);     // t1.u4
    VMCNT(4);
    BAR();

    bf16x8_t a[4][2], b0[2][2], b1[2][2];

    for (int it = 0; it < 8; ++it) {
        const int kO = it * 128 + 64;
        int kP2 = it * 128 + 128; if (kP2 > K - BK) kP2 = K - BK;  // clamp: garbage into
        int kP3 = it * 128 + 192; if (kP3 > K - BK) kP3 = K - BK;  // dead regions, in-bounds

        // ph1: E q(0,0)
        LOAD_A(0, 0); LOAD_B(0, 0, b0);
        STAGE_B(1, 0, kO);
        BAR(); LGKM0();
        MFMA_Q(0, 0, b0);
        BAR();

        // ph2: E q(0,1)
        LOAD_B(0, 1, b1);
        STAGE_A(1, 1, kO);
        BAR(); LGKM0();
        MFMA_Q(0, 1, b1);
        BAR();

        // ph3: E q(1,1)
        LOAD_A(0, 1);
        STAGE_A(0, 0, kP2);
        BAR(); LGKM0();
        MFMA_Q(1, 1, b1);
        BAR();

        // ph4: E q(1,0); gate for tile O
        STAGE_B(0, 1, kP2);
        BAR();
        MFMA_Q(1, 0, b0);
        VMCNT(4);
        BAR();

        // ph5: O q(0,0)
        LOAD_A(1, 0); LOAD_B(1, 0, b0);
        STAGE_A(0, 1, kP2);
        BAR(); LGKM0();
        MFMA_Q(0, 0, b0);
        BAR();

        // ph6: O q(0,1)
        LOAD_B(1, 1, b1);
        STAGE_B(0, 0, kP2);
        BAR(); LGKM0();
        MFMA_Q(0, 1, b1);
        BAR();

        // ph7: O q(1,1)
        LOAD_A(1, 1);
        STAGE_A(1, 0, kP3);
        BAR(); LGKM0();
        MFMA_Q(1, 1, b1);
        BAR();

        // ph8: O q(1,0); gate for tile E+2
        STAGE_B(1, 1, kP3);
        BAR();
        MFMA_Q(1, 0, b0);
        VMCNT(4);
        BAR();
    }

    // Epilogue: nontemporal dword C stores (no write-allocate line fetch, no
    // L2/L3 pollution of A/B panels). Order (i, r, j): the four 64B segments of
    // each C row issue back-to-back to maximize write-combining.
    // C/D layout (verified m89/m91): col = lane&15, row = quad*4 + reg.
    const int crow0 = bm + wm * 128 + quad * 4;
    const int ccol0 = bn + wn * 64 + l16;
#pragma unroll
    for (int i_ = 0; i_ < 8; ++i_)
#pragma unroll
      for (int r_ = 0; r_ < 4; ++r_) {
        float* rowp = &C[(size_t)(crow0 + i_ * 16 + r_) * N + ccol0];
#pragma unroll
        for (int j_ = 0; j_ < 4; ++j_)
          __builtin_nontemporal_store(acc[i_][j_][r_], rowp + j_ * 16);
      }

#undef STAGE_A
#undef STAGE_B
#undef LOAD_A
#undef LOAD_B
#undef MFMA_Q
#undef FENCE
#undef BAR
#undef LGKM0
#undef VMCNT
}

extern "C" void kernel_launch(void* const* d_in, const int* in_sizes, int n_in,
                              void* d_out, int out_size, void* d_ws, size_t ws_size,
                              hipStream_t stream) {
    const float* in_f32 = (const float*)d_in[0];   // [M,K]
    const float* w_f32  = (const float*)d_in[1];   // [N,K]
    float* out = (float*)d_out;                     // [M,N]

    __bf16* A_bf = (__bf16*)d_ws;
    __bf16* W_bf = A_bf + (size_t)M * K;

    cvt_f32_bf16<<<((size_t)(M + N) * K) / (8 * 256), 256, 0, stream>>>(in_f32, w_f32, A_bf, W_bf);

    dim3 grid(N / BN, M / BM);   // (16, 32) = 512 blocks, 1 block/CU (128 KiB LDS)
    gemm_bt<<<grid, 512, 0, stream>>>(A_bf, W_bf, out);
}